// Round 1
// baseline (288.190 us; speedup 1.0000x reference)
//
#include <hip/hip_runtime.h>

#define D_NODE 256
#define D_EDGE 128
#define D_HEAD 32
#define NN 512

// ---------------------------------------------------------------------------
// Kernel 1: LayerNorm(node) -> x; left = x@w_left + b_left; right = x@w_right + b_right
// One block per row n. 256 threads: LN reduction; 64 threads do the 64 dots.
// ---------------------------------------------------------------------------
__global__ __launch_bounds__(256) void ln_proj_kernel(
    const float* __restrict__ node, const float* __restrict__ ln_w,
    const float* __restrict__ ln_b, const float* __restrict__ w_left,
    const float* __restrict__ b_left, const float* __restrict__ w_right,
    const float* __restrict__ b_right, float* __restrict__ left,
    float* __restrict__ right) {
  __shared__ float xs[D_NODE];
  __shared__ float red[10];
  const int n = blockIdx.x;
  const int t = threadIdx.x;
  float v = node[n * D_NODE + t];
  float s = v, ss = v * v;
#pragma unroll
  for (int o = 32; o > 0; o >>= 1) {
    s += __shfl_down(s, o);
    ss += __shfl_down(ss, o);
  }
  if ((t & 63) == 0) {
    red[t >> 6] = s;
    red[4 + (t >> 6)] = ss;
  }
  __syncthreads();
  if (t == 0) {
    float S = red[0] + red[1] + red[2] + red[3];
    float SS = red[4] + red[5] + red[6] + red[7];
    float mu = S * (1.0f / D_NODE);
    float var = SS * (1.0f / D_NODE) - mu * mu;
    red[8] = mu;
    red[9] = rsqrtf(var + 1e-5f);
  }
  __syncthreads();
  const float mu = red[8], rs = red[9];
  xs[t] = (v - mu) * rs * ln_w[t] + ln_b[t];
  __syncthreads();
  if (t < 64) {
    const int c = t & 31;
    const bool isL = (t < 32);
    const float* w = isL ? w_left : w_right;
    float acc = isL ? b_left[c] : b_right[c];
#pragma unroll 8
    for (int d = 0; d < D_NODE; ++d) acc = fmaf(xs[d], w[d * D_HEAD + c], acc);
    (isL ? left : right)[n * D_HEAD + c] = acc;
  }
}

// ---------------------------------------------------------------------------
// Kernel 2: tmp[m,i,e] = sum_j right[m,j] * w_out[(i*32+j)*128 + e]
// Grid (256, 2): block covers m in {2bx, 2bx+1}, i in [16*by, 16*by+16).
// Thread: e4 = t&31 (float4 over e), io = t>>5 -> 4 i's. w_out stays in L2.
// ---------------------------------------------------------------------------
__global__ __launch_bounds__(128) void rw_kernel(
    const float* __restrict__ right, const float* __restrict__ w_out,
    float* __restrict__ tmp) {
  const int m0 = blockIdx.x * 2;
  const int ibase = blockIdx.y * 16;
  const int t = threadIdx.x;
  const int e4 = t & 31;
  const int io = t >> 5;
  const float* r0 = right + m0 * D_HEAD;  // uniform -> s_load
  const float* r1 = r0 + D_HEAD;
  for (int k = 0; k < 4; ++k) {
    const int i = ibase + io * 4 + k;
    const float4* wp = (const float4*)(w_out + i * D_HEAD * D_EDGE) + e4;
    float4 a0 = {0.f, 0.f, 0.f, 0.f};
    float4 a1 = {0.f, 0.f, 0.f, 0.f};
#pragma unroll
    for (int j = 0; j < D_HEAD; ++j) {
      const float4 w4 = wp[j * (D_EDGE / 4)];
      const float rj0 = r0[j];
      const float rj1 = r1[j];
      a0.x = fmaf(rj0, w4.x, a0.x);
      a0.y = fmaf(rj0, w4.y, a0.y);
      a0.z = fmaf(rj0, w4.z, a0.z);
      a0.w = fmaf(rj0, w4.w, a0.w);
      a1.x = fmaf(rj1, w4.x, a1.x);
      a1.y = fmaf(rj1, w4.y, a1.y);
      a1.z = fmaf(rj1, w4.z, a1.z);
      a1.w = fmaf(rj1, w4.w, a1.w);
    }
    ((float4*)(tmp + (m0 * D_HEAD + i) * D_EDGE))[e4] = a0;
    ((float4*)(tmp + ((m0 + 1) * D_HEAD + i) * D_EDGE))[e4] = a1;
  }
}

// ---------------------------------------------------------------------------
// Kernel 3 (workhorse, memory-bound): out[n,m,e] =
//   b_out[e] + edge[n,m,e] + sum_i left[n,i] * tmp[m,i,e]
// Grid (512 m, 4 nchunk), 128 threads. Thread: e2 = t&63 (float2 over e),
// wave handles one n at a time (n wave-uniform => left via s_load).
// tmp[m,:,e] lives in 64 VGPRs, loaded once per block. Edge prefetched 1 iter ahead.
// ---------------------------------------------------------------------------
__global__ __launch_bounds__(128) void fuse_kernel(
    const float* __restrict__ left, const float* __restrict__ tmp,
    const float* __restrict__ b_out, const float* __restrict__ edge,
    float* __restrict__ out) {
  const int m = blockIdx.x;
  const int n0 = blockIdx.y * 128;
  const int t = threadIdx.x;
  const int e2 = t & 63;
  const int nsub = __builtin_amdgcn_readfirstlane(t >> 6);  // wave-uniform 0/1
  float2 rT[D_HEAD];
  const float2* tp = (const float2*)(tmp + m * D_HEAD * D_EDGE) + e2;
#pragma unroll
  for (int i = 0; i < D_HEAD; ++i) rT[i] = tp[i * (D_EDGE / 2)];
  const float2 be = ((const float2*)b_out)[e2];
  const float2* edge2 = (const float2*)edge;
  float2* out2 = (float2*)out;
  const int stride = 2 * NN * (D_EDGE / 2);  // advance 2 n's
  int idx = ((n0 + nsub) * NN + m) * (D_EDGE / 2) + e2;
  float2 ev = edge2[idx];
  for (int nn = nsub; nn < 128; nn += 2) {
    const int nidx = idx + stride;
    const int pidx = (nn + 2 < 128) ? nidx : idx;  // uniform select, safe tail
    const float2 evn = edge2[pidx];                // prefetch next edge row
    const float* lp = left + (n0 + nn) * D_HEAD;   // uniform -> s_load x32
    float2 acc = be;
#pragma unroll
    for (int i = 0; i < D_HEAD; ++i) {
      const float l = lp[i];
      acc.x = fmaf(l, rT[i].x, acc.x);
      acc.y = fmaf(l, rT[i].y, acc.y);
    }
    acc.x += ev.x;
    acc.y += ev.y;
    out2[idx] = acc;
    ev = evn;
    idx = nidx;
  }
}

extern "C" void kernel_launch(void* const* d_in, const int* in_sizes, int n_in,
                              void* d_out, int out_size, void* d_ws, size_t ws_size,
                              hipStream_t stream) {
  const float* node    = (const float*)d_in[0];
  const float* edge    = (const float*)d_in[1];
  const float* ln_w    = (const float*)d_in[2];
  const float* ln_b    = (const float*)d_in[3];
  const float* w_left  = (const float*)d_in[4];
  const float* b_left  = (const float*)d_in[5];
  const float* w_right = (const float*)d_in[6];
  const float* b_right = (const float*)d_in[7];
  const float* w_out   = (const float*)d_in[8];
  const float* b_out   = (const float*)d_in[9];
  float* out = (float*)d_out;

  float* left  = (float*)d_ws;                 // 512*32 floats
  float* right = left + NN * D_HEAD;           // 512*32 floats
  float* tmp   = right + NN * D_HEAD;          // 512*32*128 floats (8 MB)

  ln_proj_kernel<<<NN, 256, 0, stream>>>(node, ln_w, ln_b, w_left, b_left,
                                         w_right, b_right, left, right);
  rw_kernel<<<dim3(NN / 2, 2), 128, 0, stream>>>(right, w_out, tmp);
  fuse_kernel<<<dim3(NN, 4), 128, 0, stream>>>(left, tmp, b_out, edge, out);
}

// Round 2
// 280.785 us; speedup vs baseline: 1.0264x; 1.0264x over previous
//
#include <hip/hip_runtime.h>

#define D_NODE 256
#define D_EDGE 128
#define D_HEAD 32
#define NN 512

// ---------------------------------------------------------------------------
// Kernel 1: LayerNorm(node) -> x; leftT[i][n] = (x@w_left + b_left)^T;
//           right[n][j] = x@w_right + b_right.
// One block per row n, 256 threads. Projection uses all 256 threads:
// 64 output cols x 4 d-quarters, reduced through LDS.
// ---------------------------------------------------------------------------
__global__ __launch_bounds__(256) void ln_proj_kernel(
    const float* __restrict__ node, const float* __restrict__ ln_w,
    const float* __restrict__ ln_b, const float* __restrict__ w_left,
    const float* __restrict__ b_left, const float* __restrict__ w_right,
    const float* __restrict__ b_right, float* __restrict__ leftT,
    float* __restrict__ right) {
  __shared__ float xs[D_NODE];
  __shared__ float red[10];
  __shared__ float part[4][64];
  const int n = blockIdx.x;
  const int t = threadIdx.x;
  float v = node[n * D_NODE + t];
  float s = v, ss = v * v;
#pragma unroll
  for (int o = 32; o > 0; o >>= 1) {
    s += __shfl_down(s, o);
    ss += __shfl_down(ss, o);
  }
  if ((t & 63) == 0) {
    red[t >> 6] = s;
    red[4 + (t >> 6)] = ss;
  }
  __syncthreads();
  if (t == 0) {
    float S = red[0] + red[1] + red[2] + red[3];
    float SS = red[4] + red[5] + red[6] + red[7];
    float mu = S * (1.0f / D_NODE);
    float var = SS * (1.0f / D_NODE) - mu * mu;
    red[8] = mu;
    red[9] = rsqrtf(var + 1e-5f);
  }
  __syncthreads();
  const float mu = red[8], rs = red[9];
  xs[t] = (v - mu) * rs * ln_w[t] + ln_b[t];
  __syncthreads();
  {
    const int col = t & 63;
    const int q = t >> 6;
    const int c = col & 31;
    const float* w = (col < 32) ? w_left : w_right;
    float acc = 0.f;
    const int d0 = q * 64;
#pragma unroll 8
    for (int d = d0; d < d0 + 64; ++d) acc = fmaf(xs[d], w[d * D_HEAD + c], acc);
    part[q][col] = acc;
  }
  __syncthreads();
  if (t < 64) {
    const int c = t & 31;
    const bool isL = (t < 32);
    float acc = part[0][t] + part[1][t] + part[2][t] + part[3][t] +
                (isL ? b_left[c] : b_right[c]);
    if (isL)
      leftT[c * NN + n] = acc;  // transposed for scalar loads in fuse
    else
      right[n * D_HEAD + c] = acc;
  }
}

// ---------------------------------------------------------------------------
// Kernel 2: tmp[m,i,e] = sum_j right[m,j] * w_out[(i*32+j)*128 + e]
// One block per m, 256 threads: e4 = t&31 (float4 over e), i8 = t>>5 -> 4 i's.
// right[m,:] wave-uniform -> s_load; w_out (512 KB) L2-resident.
// ---------------------------------------------------------------------------
__global__ __launch_bounds__(256) void rw_kernel(
    const float* __restrict__ right, const float* __restrict__ w_out,
    float* __restrict__ tmp) {
  const int m = blockIdx.x;
  const int t = threadIdx.x;
  const int e4 = t & 31;
  const int i8 = t >> 5;
  const float* r = right + m * D_HEAD;  // uniform -> s_load
#pragma unroll
  for (int k = 0; k < 4; ++k) {
    const int i = i8 * 4 + k;
    const float4* wp = (const float4*)(w_out + i * D_HEAD * D_EDGE) + e4;
    float4 a = {0.f, 0.f, 0.f, 0.f};
#pragma unroll
    for (int j = 0; j < D_HEAD; ++j) {
      const float4 w4 = wp[j * (D_EDGE / 4)];
      const float rj = r[j];
      a.x = fmaf(rj, w4.x, a.x);
      a.y = fmaf(rj, w4.y, a.y);
      a.z = fmaf(rj, w4.z, a.z);
      a.w = fmaf(rj, w4.w, a.w);
    }
    ((float4*)(tmp + (m * D_HEAD + i) * D_EDGE))[e4] = a;
  }
}

// ---------------------------------------------------------------------------
// Kernel 3 (workhorse): out[n,m,e] = b_out[e] + edge[n,m,e]
//                                  + sum_i leftT[i][n] * tmp[m,i,e]
// Grid (512 m, 16 nchunk), 256 threads = 4 waves. Wave owns 8 consecutive
// n-rows; lane = e2 (float2 over all 128 e). 8 edge rows loaded up front
// (4 KB in flight/wave). left via wave-uniform s_loads from leftT.
// tmp[m] slice (16 KB) is L1-resident after first wave.
// ---------------------------------------------------------------------------
__global__ __launch_bounds__(256) void fuse_kernel(
    const float* __restrict__ leftT, const float* __restrict__ tmp,
    const float* __restrict__ b_out, const float* __restrict__ edge,
    float* __restrict__ out) {
  const int m = blockIdx.x;
  const int wave = __builtin_amdgcn_readfirstlane(threadIdx.x >> 6);
  const int lane = threadIdx.x & 63;
  const int nbase = blockIdx.y * 32 + wave * 8;

  const float2* tp = (const float2*)(tmp + m * D_HEAD * D_EDGE) + lane;
  const float2 be = ((const float2*)b_out)[lane];
  const float2* edge2 = (const float2*)edge;
  float2* out2 = (float2*)out;
  const long rowstride = (long)NN * (D_EDGE / 2);
  const long base = ((long)nbase * NN + m) * (D_EDGE / 2) + lane;

  float2 ed[8];
#pragma unroll
  for (int r = 0; r < 8; ++r) ed[r] = edge2[base + r * rowstride];

  float2 acc[8];
#pragma unroll
  for (int r = 0; r < 8; ++r) acc[r] = be;

  const float* lB = leftT + nbase;  // wave-uniform base: lB[i*NN + r] -> s_load
#pragma unroll
  for (int i = 0; i < D_HEAD; ++i) {
    const float2 rt = tp[i * (D_EDGE / 2)];
#pragma unroll
    for (int r = 0; r < 8; ++r) {
      const float l = lB[i * NN + r];
      acc[r].x = fmaf(l, rt.x, acc[r].x);
      acc[r].y = fmaf(l, rt.y, acc[r].y);
    }
  }
#pragma unroll
  for (int r = 0; r < 8; ++r) {
    acc[r].x += ed[r].x;
    acc[r].y += ed[r].y;
    out2[base + r * rowstride] = acc[r];
  }
}

extern "C" void kernel_launch(void* const* d_in, const int* in_sizes, int n_in,
                              void* d_out, int out_size, void* d_ws, size_t ws_size,
                              hipStream_t stream) {
  const float* node    = (const float*)d_in[0];
  const float* edge    = (const float*)d_in[1];
  const float* ln_w    = (const float*)d_in[2];
  const float* ln_b    = (const float*)d_in[3];
  const float* w_left  = (const float*)d_in[4];
  const float* b_left  = (const float*)d_in[5];
  const float* w_right = (const float*)d_in[6];
  const float* b_right = (const float*)d_in[7];
  const float* w_out   = (const float*)d_in[8];
  const float* b_out   = (const float*)d_in[9];
  float* out = (float*)d_out;

  float* leftT = (float*)d_ws;                  // [32][512]
  float* right = leftT + D_HEAD * NN;           // [512][32]
  float* tmp   = right + NN * D_HEAD;           // [512][32][128] (8 MB)

  ln_proj_kernel<<<NN, 256, 0, stream>>>(node, ln_w, ln_b, w_left, b_left,
                                         w_right, b_right, leftT, right);
  rw_kernel<<<NN, 256, 0, stream>>>(right, w_out, tmp);
  fuse_kernel<<<dim3(NN, 16), 256, 0, stream>>>(leftT, tmp, b_out, edge, out);
}

// Round 3
// 271.909 us; speedup vs baseline: 1.0599x; 1.0326x over previous
//
#include <hip/hip_runtime.h>

#define D_NODE 256
#define D_EDGE 128
#define D_HEAD 32
#define NN 512

typedef float f4v __attribute__((ext_vector_type(4)));

// ---------------------------------------------------------------------------
// Kernel 1: LayerNorm(node) -> x; left = x@w_left + b_left (natural layout);
//           right = x@w_right + b_right. One block per row n, 256 threads.
// ---------------------------------------------------------------------------
__global__ __launch_bounds__(256) void ln_proj_kernel(
    const float* __restrict__ node, const float* __restrict__ ln_w,
    const float* __restrict__ ln_b, const float* __restrict__ w_left,
    const float* __restrict__ b_left, const float* __restrict__ w_right,
    const float* __restrict__ b_right, float* __restrict__ left,
    float* __restrict__ right) {
  __shared__ float xs[D_NODE];
  __shared__ float red[10];
  __shared__ float part[4][64];
  const int n = blockIdx.x;
  const int t = threadIdx.x;
  float v = node[n * D_NODE + t];
  float s = v, ss = v * v;
#pragma unroll
  for (int o = 32; o > 0; o >>= 1) {
    s += __shfl_down(s, o);
    ss += __shfl_down(ss, o);
  }
  if ((t & 63) == 0) {
    red[t >> 6] = s;
    red[4 + (t >> 6)] = ss;
  }
  __syncthreads();
  if (t == 0) {
    float S = red[0] + red[1] + red[2] + red[3];
    float SS = red[4] + red[5] + red[6] + red[7];
    float mu = S * (1.0f / D_NODE);
    float var = SS * (1.0f / D_NODE) - mu * mu;
    red[8] = mu;
    red[9] = rsqrtf(var + 1e-5f);
  }
  __syncthreads();
  const float mu = red[8], rs = red[9];
  xs[t] = (v - mu) * rs * ln_w[t] + ln_b[t];
  __syncthreads();
  {
    const int col = t & 63;
    const int q = t >> 6;
    const int c = col & 31;
    const float* w = (col < 32) ? w_left : w_right;
    float acc = 0.f;
    const int d0 = q * 64;
#pragma unroll 8
    for (int d = d0; d < d0 + 64; ++d) acc = fmaf(xs[d], w[d * D_HEAD + c], acc);
    part[q][col] = acc;
  }
  __syncthreads();
  if (t < 64) {
    const int c = t & 31;
    const bool isL = (t < 32);
    float acc = part[0][t] + part[1][t] + part[2][t] + part[3][t] +
                (isL ? b_left[c] : b_right[c]);
    (isL ? left : right)[n * D_HEAD + c] = acc;
  }
}

// ---------------------------------------------------------------------------
// Kernel 2: tmp[m,i,e] = sum_j right[m,j] * w_out[(i*32+j)*128 + e]
// Block covers 4 m's and 8 i's -> each w_out line reused 4x in registers.
// Grid (128, 4), 256 threads: e4 = t&31 (float4 over e), i = i0 + (t>>5).
// ---------------------------------------------------------------------------
__global__ __launch_bounds__(256) void rw_kernel(
    const float* __restrict__ right, const float* __restrict__ w_out,
    float* __restrict__ tmp) {
  const int m0 = blockIdx.x * 4;
  const int i = blockIdx.y * 8 + (threadIdx.x >> 5);
  const int e4 = threadIdx.x & 31;
  const float4* wp = (const float4*)(w_out + i * D_HEAD * D_EDGE) + e4;
  const float* r = right + m0 * D_HEAD;  // wave-uniform -> s_load
  float4 a0 = {0, 0, 0, 0}, a1 = {0, 0, 0, 0}, a2 = {0, 0, 0, 0},
         a3 = {0, 0, 0, 0};
#pragma unroll
  for (int j = 0; j < D_HEAD; ++j) {
    const float4 w4 = wp[j * (D_EDGE / 4)];
    const float r0 = r[j], r1 = r[32 + j], r2 = r[64 + j], r3 = r[96 + j];
    a0.x = fmaf(r0, w4.x, a0.x); a0.y = fmaf(r0, w4.y, a0.y);
    a0.z = fmaf(r0, w4.z, a0.z); a0.w = fmaf(r0, w4.w, a0.w);
    a1.x = fmaf(r1, w4.x, a1.x); a1.y = fmaf(r1, w4.y, a1.y);
    a1.z = fmaf(r1, w4.z, a1.z); a1.w = fmaf(r1, w4.w, a1.w);
    a2.x = fmaf(r2, w4.x, a2.x); a2.y = fmaf(r2, w4.y, a2.y);
    a2.z = fmaf(r2, w4.z, a2.z); a2.w = fmaf(r2, w4.w, a2.w);
    a3.x = fmaf(r3, w4.x, a3.x); a3.y = fmaf(r3, w4.y, a3.y);
    a3.z = fmaf(r3, w4.z, a3.z); a3.w = fmaf(r3, w4.w, a3.w);
  }
  ((float4*)(tmp + ((m0 + 0) * D_HEAD + i) * D_EDGE))[e4] = a0;
  ((float4*)(tmp + ((m0 + 1) * D_HEAD + i) * D_EDGE))[e4] = a1;
  ((float4*)(tmp + ((m0 + 2) * D_HEAD + i) * D_EDGE))[e4] = a2;
  ((float4*)(tmp + ((m0 + 3) * D_HEAD + i) * D_EDGE))[e4] = a3;
}

// ---------------------------------------------------------------------------
// Kernel 3 (workhorse, streaming): out[n,m,e] = b_out[e] + edge[n,m,e]
//                                + sum_i left[n,i] * tmp[m,i,e]
// Block owns an m-PAIR (edge/out rows for m0,m0+1 are contiguous -> float4,
// 1 KB per wave-instruction) and a 128-row n-chunk. tmp pair staged in LDS
// (32 KB) once, read via ds_read_b128. Each wave: 32 rows in 4 groups of 8,
// next group's edge (8 KB) register-prefetched while computing the current —
// no barriers in the loop, continuous HBM streaming.
// Lane: mh = lane>>5 (which m of pair), e4 = lane&31 (float4 over e).
// ---------------------------------------------------------------------------
__global__ __launch_bounds__(256) void fuse_kernel(
    const float* __restrict__ left, const float* __restrict__ tmp,
    const float* __restrict__ b_out, const float* __restrict__ edge,
    float* __restrict__ out) {
  __shared__ float tl[2 * D_HEAD * D_EDGE];  // 32 KB
  const int m0 = blockIdx.x * 2;
  const int t = threadIdx.x;
  {  // stage tmp[m0] and tmp[m0+1] (contiguous 8192 floats)
    const float4* ts = (const float4*)(tmp + m0 * D_HEAD * D_EDGE);
    float4* td = (float4*)tl;
#pragma unroll
    for (int k = 0; k < 8; ++k) td[t + 256 * k] = ts[t + 256 * k];
  }
  const int lane = t & 63;
  const int wv = __builtin_amdgcn_readfirstlane(t >> 6);
  const int e4 = lane & 31;
  const int mh = lane >> 5;
  const int n0 = blockIdx.y * 128 + wv * 32;
  const float4 be = ((const float4*)b_out)[e4];
  const float* tb = tl + mh * (D_HEAD * D_EDGE) + e4 * 4;
  const float4* edge4 = (const float4*)edge;
  float4* out4 = (float4*)out;
  const int rowstr = NN * (D_EDGE / 4);  // float4 stride for n -> n+1
  const int base = (n0 * NN + m0) * (D_EDGE / 4) + lane;

  float4 eb[2][8];
#pragma unroll
  for (int r = 0; r < 8; ++r) eb[0][r] = edge4[base + r * rowstr];
  __syncthreads();

#pragma unroll
  for (int g = 0; g < 4; ++g) {
    const int cur = g & 1;
    const int gb = base + g * 8 * rowstr;
    if (g < 3) {  // prefetch next group's edge rows
#pragma unroll
      for (int r = 0; r < 8; ++r)
        eb[cur ^ 1][r] = edge4[gb + (8 + r) * rowstr];
    }
    float4 acc[8];
#pragma unroll
    for (int r = 0; r < 8; ++r) acc[r] = be;
    const float* lp = left + (n0 + g * 8) * D_HEAD;  // uniform -> s_load
#pragma unroll 4
    for (int i = 0; i < D_HEAD; ++i) {
      const float4 tv = *(const float4*)(tb + i * D_EDGE);
#pragma unroll
      for (int r = 0; r < 8; ++r) {
        const float l = lp[r * D_HEAD + i];
        acc[r].x = fmaf(l, tv.x, acc[r].x);
        acc[r].y = fmaf(l, tv.y, acc[r].y);
        acc[r].z = fmaf(l, tv.z, acc[r].z);
        acc[r].w = fmaf(l, tv.w, acc[r].w);
      }
    }
#pragma unroll
    for (int r = 0; r < 8; ++r) {
      acc[r].x += eb[cur][r].x;
      acc[r].y += eb[cur][r].y;
      acc[r].z += eb[cur][r].z;
      acc[r].w += eb[cur][r].w;
      __builtin_nontemporal_store(*(const f4v*)&acc[r],
                                  (f4v*)(out4 + gb + r * rowstr));
    }
  }
}

extern "C" void kernel_launch(void* const* d_in, const int* in_sizes, int n_in,
                              void* d_out, int out_size, void* d_ws, size_t ws_size,
                              hipStream_t stream) {
  const float* node    = (const float*)d_in[0];
  const float* edge    = (const float*)d_in[1];
  const float* ln_w    = (const float*)d_in[2];
  const float* ln_b    = (const float*)d_in[3];
  const float* w_left  = (const float*)d_in[4];
  const float* b_left  = (const float*)d_in[5];
  const float* w_right = (const float*)d_in[6];
  const float* b_right = (const float*)d_in[7];
  const float* w_out   = (const float*)d_in[8];
  const float* b_out   = (const float*)d_in[9];
  float* out = (float*)d_out;

  float* left  = (float*)d_ws;                 // [512][32]
  float* right = left + NN * D_HEAD;           // [512][32]
  float* tmp   = right + NN * D_HEAD;          // [512][32][128] (8 MB)

  ln_proj_kernel<<<NN, 256, 0, stream>>>(node, ln_w, ln_b, w_left, b_left,
                                         w_right, b_right, left, right);
  rw_kernel<<<dim3(NN / 4, 4), 256, 0, stream>>>(right, w_out, tmp);
  fuse_kernel<<<dim3(NN / 2, 4), 256, 0, stream>>>(left, tmp, b_out, edge, out);
}